// Round 5
// baseline (582.023 us; speedup 1.0000x reference)
//
#include <hip/hip_runtime.h>

#define THREADS 256
#define MU_C  0.1f
#define EPS_C 0.01f

typedef short bf16x8 __attribute__((ext_vector_type(8)));
typedef bf16x8 bf16x8_a __attribute__((may_alias));
typedef float f32x4 __attribute__((ext_vector_type(4)));
typedef f32x4 f32x4_a __attribute__((may_alias));
typedef unsigned uint2v __attribute__((ext_vector_type(2)));
typedef uint2v uint2_a __attribute__((may_alias));
typedef unsigned u32_a __attribute__((may_alias));

#define MFMA(a, b, c) __builtin_amdgcn_mfma_f32_16x16x32_bf16((a), (b), (c), 0, 0, 0)

// ---- prepacked tile enumeration (1 tile = 64 lanes x 16B = 1 KB in d_ws) ----
#define T_WH1   0     // 8  : K=16pad32, bias bh1 at k=16
#define T_WH2   8     // 4  : K=128
#define T_WH2T  12    // 8  : K=16pad32 (no bias)
#define T_WH1T  20    // 4  : K=128
#define T_W1JR  24    // 4  : K=16pad32, bias b1jr at k=16
#define T_W2JR  28    // 8  : K=64
#define T_JMN   36    // 32 : Jm normal slabs n=0..15
#define T_JMT   68    // 32 : Jm transposed slabs t=0..15
#define T_RFN   100   // 32 : Rf normal
#define T_RFT   132   // 32 : Rf transposed
#define T_W1B   164   // 4  : K=16pad32, bias b1b at k=16
#define T_W2B   168   // 8  : K=64
#define T_BMN   176   // 16 : Bmat normal n=0..7
#define T_BMT   192   // 16 : Bmat transposed m=0..7
#define NTILES  208

__device__ __forceinline__ float ftanh(float x) {
    float e = __builtin_amdgcn_exp2f(x * 2.88539008177792681472f);
    return 1.0f - 2.0f * __builtin_amdgcn_rcpf(e + 1.0f);
}
__device__ __forceinline__ short bfrn(float f) {
    unsigned u = __float_as_uint(f);
    return (short)((u + 0x8000u) >> 16);
}
__device__ __forceinline__ float bf2f(unsigned lo16) {
    return __uint_as_float(lo16 << 16);
}
__device__ __forceinline__ unsigned pk2(float lo, float hi) {
    return ((unsigned)(unsigned short)bfrn(hi) << 16) | (unsigned short)bfrn(lo);
}
__device__ __forceinline__ bf16x8 wsB(const short* __restrict__ ws, int tile, int lane) {
    return *reinterpret_cast<const bf16x8*>(ws + (size_t)((tile << 6) + lane) * 8);
}
__device__ __forceinline__ bf16x8 ldsA(const short* base, int strideS, int lane, int k0) {
    return *reinterpret_cast<const bf16x8_a*>(base + (lane & 15) * strideS + k0 + (lane >> 4) * 8);
}

// ==================== weight pre-pack kernel ====================
__global__ __launch_bounds__(256)
void pack_weights(const float* __restrict__ Wh1, const float* __restrict__ bh1,
                  const float* __restrict__ Wh2,
                  const float* __restrict__ W1jr, const float* __restrict__ b1jr,
                  const float* __restrict__ W2jr, const float* __restrict__ W3jr,
                  const float* __restrict__ W1b, const float* __restrict__ b1b,
                  const float* __restrict__ W2b, const float* __restrict__ W3b,
                  short* __restrict__ ws)
{
    const int id = blockIdx.x * 256 + threadIdx.x;
    if (id >= NTILES * 64) return;
    const int tile = id >> 6, lane = id & 63;
    const int j2 = lane & 15, g = lane >> 4;
    bf16x8 f;
#pragma unroll
    for (int jj = 0; jj < 8; ++jj) {
        const int k = g * 8 + jj;
        float x = 0.f;
        if (tile < T_WH2) {
            int n0 = (tile - T_WH1) * 16;
            if (g < 2) x = Wh1[(n0 + j2) * 16 + k];
            else if (k == 16) x = bh1[n0 + j2];
        } else if (tile < T_WH2T) {
            int kt = tile - T_WH2;
            x = Wh2[j2 * 128 + kt * 32 + k];
        } else if (tile < T_WH1T) {
            if (g < 2) x = Wh2[k * 128 + (tile - T_WH2T) * 16 + j2];
        } else if (tile < T_W1JR) {
            int kt = tile - T_WH1T;
            x = Wh1[(kt * 32 + k) * 16 + j2];
        } else if (tile < T_W2JR) {
            int n0 = (tile - T_W1JR) * 16;
            if (g < 2) x = W1jr[(n0 + j2) * 16 + k];
            else if (k == 16) x = b1jr[n0 + j2];
        } else if (tile < T_JMN) {
            int q = tile - T_W2JR; int nt = q >> 1, kt = q & 1;
            x = W2jr[(nt * 16 + j2) * 64 + kt * 32 + k];
        } else if (tile < T_JMT) {
            int q = tile - T_JMN; int n = q >> 1, kt = q & 1;
            x = W3jr[(n * 16 + j2) * 64 + kt * 32 + k];
        } else if (tile < T_RFN) {
            int q = tile - T_JMT; int t = q >> 1, kt = q & 1;
            x = W3jr[(j2 * 16 + t) * 64 + kt * 32 + k];
        } else if (tile < T_RFT) {
            int q = tile - T_RFN; int n = q >> 1, kt = q & 1;
            x = W3jr[(256 + n * 16 + j2) * 64 + kt * 32 + k];
        } else if (tile < T_W1B) {
            int q = tile - T_RFT; int t = q >> 1, kt = q & 1;
            x = W3jr[(256 + j2 * 16 + t) * 64 + kt * 32 + k];
        } else if (tile < T_W2B) {
            int n0 = (tile - T_W1B) * 16;
            if (g < 2) x = W1b[(n0 + j2) * 16 + k];
            else if (k == 16) x = b1b[n0 + j2];
        } else if (tile < T_BMN) {
            int q = tile - T_W2B; int nt = q >> 1, kt = q & 1;
            x = W2b[(nt * 16 + j2) * 64 + kt * 32 + k];
        } else if (tile < T_BMT) {
            int q = tile - T_BMN; int n = q >> 1, kt = q & 1;
            x = W3b[(n * 16 + j2) * 64 + kt * 32 + k];
        } else {
            int q = tile - T_BMT; int m = q >> 1, kt = q & 1;
            x = W3b[(j2 * 8 + m) * 64 + kt * 32 + k];
        }
        f[jj] = bfrn(x);
    }
    reinterpret_cast<bf16x8*>(ws)[id] = f;
}

// ==================== main kernel ====================
// Activations stored [batch row][feature k] bf16; weights are the MFMA A
// operand, activations the B operand -> C = [feature rows x batch cols],
// lane (j2,g) holds feats g*4..+3 of batch row j2 (all epilogues lane-local).
struct __align__(16) WaveLds {
    short zt [16 * 40];    // z  bf16, col16 = 1.0 (bias slot), 17..31 = 0
    short fvt[16 * 40];    // fv bf16, cols 16..31 = 0
    char  act[4608];       // overlay: t1[16][136]s | {h1t[16][72]s, h2t[16][72]s @2304} | rfv f32[16][20] @2304
    float gHf[16 * 20];    // gH f32 [batch][feat]
};
struct __align__(16) BlockLds {
    WaveLds w[4];
    float bias[768];       // 0 b2jr(64) | 64 b3jr(512) | 576 b2b(64) | 640 b3b(128)
};

__global__ __launch_bounds__(THREADS, 4)
void ph_mfma_kernel(const float* __restrict__ zg, const float* __restrict__ ug,
                    const float* __restrict__ b2jr, const float* __restrict__ b3jr,
                    const float* __restrict__ b2b, const float* __restrict__ b3b,
                    const short* __restrict__ ws,
                    float* __restrict__ out, int B)
{
    __shared__ BlockLds L;
    const int tid  = threadIdx.x;
    const int lane = tid & 63;
    const int wid  = tid >> 6;
    const int j2   = lane & 15;
    const int g    = lane >> 4;
    const int g4   = g * 4;
    const int rowbase = blockIdx.x * 64 + wid * 16;
    if (blockIdx.x * 64 >= B) return;

    WaveLds& Wv = L.w[wid];
    short* t1s = (short*)Wv.act;                 // stride 136
    short* h1t = (short*)Wv.act;                 // stride 72
    short* h2t = (short*)(Wv.act + 2304);        // stride 72
    float* rfv = (float*)(Wv.act + 2304);        // stride 20  (overlays h2t; disjoint lifetime)

    // ---- block prologue: biases ----
    for (int i = tid; i < 768; i += THREADS) {
        float v;
        if      (i < 64)  v = b2jr[i];
        else if (i < 576) v = b3jr[i - 64];
        else if (i < 640) v = b2b[i - 576];
        else              v = b3b[i - 640];
        L.bias[i] = v;
    }
    // ---- per-wave prologue ----
    if (lane < 16) {   // zt pad: col16 = 1.0, 17..31 = 0 ; fvt pad: 16..31 = 0
        u32_a* p = (u32_a*)&Wv.zt[lane * 40 + 16];
        p[0] = 0x00003F80u;
#pragma unroll
        for (int i = 1; i < 8; ++i) p[i] = 0u;
        u32_a* q = (u32_a*)&Wv.fvt[lane * 40 + 16];
#pragma unroll
        for (int i = 0; i < 8; ++i) q[i] = 0u;
    }
    float zReg[4];
    {
        float4 zv = *reinterpret_cast<const float4*>(zg + (size_t)(rowbase + j2) * 16 + g4);
        zReg[0] = zv.x; zReg[1] = zv.y; zReg[2] = zv.z; zReg[3] = zv.w;
        *(uint2_a*)&Wv.zt[j2 * 40 + g4] = (uint2v){pk2(zv.x, zv.y), pk2(zv.z, zv.w)};
    }
    float uReg[8];
    {
        const float4* up = reinterpret_cast<const float4*>(ug + (size_t)(rowbase + j2) * 8);
        float4 u0 = up[0], u1 = up[1];
        uReg[0]=u0.x; uReg[1]=u0.y; uReg[2]=u0.z; uReg[3]=u0.w;
        uReg[4]=u1.x; uReg[5]=u1.y; uReg[6]=u1.z; uReg[7]=u1.w;
    }
    __syncthreads();

#pragma unroll 1
    for (int pass = 0; pass < 2; ++pass) {
        bf16x8 bZ = ldsA(Wv.zt, 40, lane, 0);
        float dzAcc[4], fvReg[4];
        unsigned tPk[16];

        // ---- step1: t1 = tanh(Wh1 z + bh1)  [feat 128 x batch 16], bias via k16 ----
#pragma unroll
        for (int nt = 0; nt < 8; ++nt) {
            f32x4 acc = {0.f, 0.f, 0.f, 0.f};
            acc = MFMA(wsB(ws, T_WH1 + nt, lane), bZ, acc);
            unsigned p0 = pk2(ftanh(acc[0]), ftanh(acc[1]));
            unsigned p1 = pk2(ftanh(acc[2]), ftanh(acc[3]));
            tPk[nt * 2] = p0; tPk[nt * 2 + 1] = p1;
            *(uint2_a*)&t1s[j2 * 136 + nt * 16 + g4] = (uint2v){p0, p1};
        }
        // ---- step2: fv = mu z + Wh2 t1  [16 x batch], K=128 ----
        {
            f32x4 acc = {0.f, 0.f, 0.f, 0.f};
#pragma unroll
            for (int kt = 0; kt < 4; ++kt)
                acc = MFMA(wsB(ws, T_WH2 + kt, lane), ldsA(t1s, 136, lane, kt * 32), acc);
#pragma unroll
            for (int r = 0; r < 4; ++r) fvReg[r] = acc[r] + MU_C * zReg[r];
            *(uint2_a*)&Wv.fvt[j2 * 40 + g4] = (uint2v){pk2(fvReg[0], fvReg[1]), pk2(fvReg[2], fvReg[3])};
        }
        // ---- step3: s = (1-t1^2) * (Wh2^T fv), t1 from regs, s -> t1 LDS ----
        {
            bf16x8 bF = ldsA(Wv.fvt, 40, lane, 0);
#pragma unroll
            for (int nt = 0; nt < 8; ++nt) {
                f32x4 acc = {0.f, 0.f, 0.f, 0.f};
                acc = MFMA(wsB(ws, T_WH2T + nt, lane), bF, acc);
                float t0 = bf2f(tPk[nt * 2] & 0xffffu),  t1v = bf2f(tPk[nt * 2] >> 16);
                float t2 = bf2f(tPk[nt * 2 + 1] & 0xffffu), t3 = bf2f(tPk[nt * 2 + 1] >> 16);
                unsigned p0 = pk2((1.f - t0 * t0) * acc[0], (1.f - t1v * t1v) * acc[1]);
                unsigned p1 = pk2((1.f - t2 * t2) * acc[2], (1.f - t3 * t3) * acc[3]);
                *(uint2_a*)&t1s[j2 * 136 + nt * 16 + g4] = (uint2v){p0, p1};
            }
        }
        // ---- step4: gH = mu fv + Wh1^T s  [16 x batch], K=128 ----
        {
            f32x4 acc = {0.f, 0.f, 0.f, 0.f};
#pragma unroll
            for (int kt = 0; kt < 4; ++kt)
                acc = MFMA(wsB(ws, T_WH1T + kt, lane), ldsA(t1s, 136, lane, kt * 32), acc);
            float gh0 = acc[0] + MU_C * fvReg[0], gh1 = acc[1] + MU_C * fvReg[1];
            float gh2 = acc[2] + MU_C * fvReg[2], gh3 = acc[3] + MU_C * fvReg[3];
            *(f32x4_a*)&Wv.gHf[j2 * 20 + g4] = (f32x4){gh0, gh1, gh2, gh3};
            dzAcc[0] = -EPS_C * gh0; dzAcc[1] = -EPS_C * gh1;
            dzAcc[2] = -EPS_C * gh2; dzAcc[3] = -EPS_C * gh3;
        }
        // ---- step5: h1 = tanh(W1jr z + b1jr), bias via k16 ----
#pragma unroll
        for (int nt = 0; nt < 4; ++nt) {
            f32x4 acc = {0.f, 0.f, 0.f, 0.f};
            acc = MFMA(wsB(ws, T_W1JR + nt, lane), bZ, acc);
            *(uint2_a*)&h1t[j2 * 72 + nt * 16 + g4] =
                (uint2v){pk2(ftanh(acc[0]), ftanh(acc[1])), pk2(ftanh(acc[2]), ftanh(acc[3]))};
        }
        // ---- step6: h2 = tanh(W2jr h1 + b2jr) ----
        {
            bf16x8 b0 = ldsA(h1t, 72, lane, 0);
            bf16x8 b1 = ldsA(h1t, 72, lane, 32);
#pragma unroll
            for (int nt = 0; nt < 4; ++nt) {
                f32x4 acc = {0.f, 0.f, 0.f, 0.f};
                acc = MFMA(wsB(ws, T_W2JR + nt * 2 + 0, lane), b0, acc);
                acc = MFMA(wsB(ws, T_W2JR + nt * 2 + 1, lane), b1, acc);
                *(uint2_a*)&h2t[j2 * 72 + nt * 16 + g4] =
                    (uint2v){pk2(ftanh(acc[0] + L.bias[nt * 16 + g4 + 0]),
                                 ftanh(acc[1] + L.bias[nt * 16 + g4 + 1])),
                             pk2(ftanh(acc[2] + L.bias[nt * 16 + g4 + 2]),
                                 ftanh(acc[3] + L.bias[nt * 16 + g4 + 3]))};
            }
        }
        // ---- step7: dz += (J - R) gH  (all factors lane-local / 1 LDS read per slab) ----
        {
            bf16x8 bH0 = ldsA(h2t, 72, lane, 0);
            bf16x8 bH1 = ldsA(h2t, 72, lane, 32);
            // Jm normal: dz_j -= Jm[n][j] gH[n]
#pragma unroll 2
            for (int n = 0; n < 16; ++n) {
                f32x4 acc = {0.f, 0.f, 0.f, 0.f};
                acc = MFMA(wsB(ws, T_JMN + 2 * n + 0, lane), bH0, acc);
                acc = MFMA(wsB(ws, T_JMN + 2 * n + 1, lane), bH1, acc);
                float gh = Wv.gHf[j2 * 20 + n];
#pragma unroll
                for (int r = 0; r < 4; ++r)
                    dzAcc[r] -= (acc[r] + L.bias[64 + n * 16 + g4 + r]) * gh;
            }
            // Jm transposed: dz_i += Jm[i][t] gH[t]
#pragma unroll 2
            for (int t = 0; t < 16; ++t) {
                f32x4 acc = {0.f, 0.f, 0.f, 0.f};
                acc = MFMA(wsB(ws, T_JMT + 2 * t + 0, lane), bH0, acc);
                acc = MFMA(wsB(ws, T_JMT + 2 * t + 1, lane), bH1, acc);
                float gh = Wv.gHf[j2 * 20 + t];
#pragma unroll
                for (int r = 0; r < 4; ++r)
                    dzAcc[r] += (acc[r] + L.bias[64 + (g4 + r) * 16 + t]) * gh;
            }
            // Rf normal: rfv_j = Rf[n][j] gH[n]
            {
                float rAcc[4] = {0.f, 0.f, 0.f, 0.f};
#pragma unroll 2
                for (int n = 0; n < 16; ++n) {
                    f32x4 acc = {0.f, 0.f, 0.f, 0.f};
                    acc = MFMA(wsB(ws, T_RFN + 2 * n + 0, lane), bH0, acc);
                    acc = MFMA(wsB(ws, T_RFN + 2 * n + 1, lane), bH1, acc);
                    float gh = Wv.gHf[j2 * 20 + n];
#pragma unroll
                    for (int r = 0; r < 4; ++r)
                        rAcc[r] += (acc[r] + L.bias[320 + n * 16 + g4 + r]) * gh;
                }
                *(f32x4_a*)&rfv[j2 * 20 + g4] = (f32x4){rAcc[0], rAcc[1], rAcc[2], rAcc[3]};
            }
            // Rf transposed: dz_i -= Rf[i][t] rfv[t]
#pragma unroll 2
            for (int t = 0; t < 16; ++t) {
                f32x4 acc = {0.f, 0.f, 0.f, 0.f};
                acc = MFMA(wsB(ws, T_RFT + 2 * t + 0, lane), bH0, acc);
                acc = MFMA(wsB(ws, T_RFT + 2 * t + 1, lane), bH1, acc);
                float rv = ((const f32x4_a*)0, rfv[j2 * 20 + t]);
#pragma unroll
                for (int r = 0; r < 4; ++r)
                    dzAcc[r] -= (acc[r] + L.bias[320 + (g4 + r) * 16 + t]) * rv;
            }
        }
        // ---- step8: g1,g2 (B-net, reuse h1t/h2t; rfv dead) ----
#pragma unroll
        for (int nt = 0; nt < 4; ++nt) {
            f32x4 acc = {0.f, 0.f, 0.f, 0.f};
            acc = MFMA(wsB(ws, T_W1B + nt, lane), bZ, acc);
            *(uint2_a*)&h1t[j2 * 72 + nt * 16 + g4] =
                (uint2v){pk2(ftanh(acc[0]), ftanh(acc[1])), pk2(ftanh(acc[2]), ftanh(acc[3]))};
        }
        {
            bf16x8 b0 = ldsA(h1t, 72, lane, 0);
            bf16x8 b1 = ldsA(h1t, 72, lane, 32);
#pragma unroll
            for (int nt = 0; nt < 4; ++nt) {
                f32x4 acc = {0.f, 0.f, 0.f, 0.f};
                acc = MFMA(wsB(ws, T_W2B + nt * 2 + 0, lane), b0, acc);
                acc = MFMA(wsB(ws, T_W2B + nt * 2 + 1, lane), b1, acc);
                *(uint2_a*)&h2t[j2 * 72 + nt * 16 + g4] =
                    (uint2v){pk2(ftanh(acc[0] + L.bias[576 + nt * 16 + g4 + 0]),
                                 ftanh(acc[1] + L.bias[576 + nt * 16 + g4 + 1])),
                             pk2(ftanh(acc[2] + L.bias[576 + nt * 16 + g4 + 2]),
                                 ftanh(acc[3] + L.bias[576 + nt * 16 + g4 + 3]))};
            }
        }
        // ---- step9: y (normal) and Bu (transposed) ----
        float yAcc[4] = {0.f, 0.f, 0.f, 0.f};
        {
            bf16x8 b0 = ldsA(h2t, 72, lane, 0);
            bf16x8 b1 = ldsA(h2t, 72, lane, 32);
#pragma unroll
            for (int n = 0; n < 8; ++n) {      // rows q=g4+r -> d=2n+(g>>1), m=q&7
                f32x4 acc = {0.f, 0.f, 0.f, 0.f};
                acc = MFMA(wsB(ws, T_BMN + 2 * n + 0, lane), b0, acc);
                acc = MFMA(wsB(ws, T_BMN + 2 * n + 1, lane), b1, acc);
                float gh = Wv.gHf[j2 * 20 + 2 * n + (g >> 1)];
#pragma unroll
                for (int r = 0; r < 4; ++r)
                    yAcc[r] += (acc[r] + L.bias[640 + n * 16 + g4 + r]) * gh;
            }
#pragma unroll
            for (int m = 0; m < 8; ++m) {      // rows = d; dz_d += B[d][m] u[m]
                f32x4 acc = {0.f, 0.f, 0.f, 0.f};
                acc = MFMA(wsB(ws, T_BMT + 2 * m + 0, lane), b0, acc);
                acc = MFMA(wsB(ws, T_BMT + 2 * m + 1, lane), b1, acc);
                float um = uReg[m];
#pragma unroll
                for (int r = 0; r < 4; ++r)
                    dzAcc[r] += (acc[r] + L.bias[640 + (g4 + r) * 8 + m]) * um;
            }
        }
        // ---- pass epilogue ----
        float* op = out + (size_t)(rowbase + j2) * 16 + g4;
        if (pass == 0) {
            float4 o;
            o.x = zReg[0] + 0.5f * dzAcc[0]; o.y = zReg[1] + 0.5f * dzAcc[1];
            o.z = zReg[2] + 0.5f * dzAcc[2]; o.w = zReg[3] + 0.5f * dzAcc[3];
            *reinterpret_cast<float4*>(op) = o;
#pragma unroll
            for (int r = 0; r < 4; ++r) zReg[r] += dzAcc[r];     // z1
            *(uint2_a*)&Wv.zt[j2 * 40 + g4] = (uint2v){pk2(zReg[0], zReg[1]), pk2(zReg[2], zReg[3])};
        } else {
            float4 o = *reinterpret_cast<const float4*>(op);
            o.x += 0.5f * dzAcc[0]; o.y += 0.5f * dzAcc[1];
            o.z += 0.5f * dzAcc[2]; o.w += 0.5f * dzAcc[3];
            *reinterpret_cast<float4*>(op) = o;
            float yv0 = yAcc[0] + __shfl_xor(yAcc[0], 32);
            float yv1 = yAcc[1] + __shfl_xor(yAcc[1], 32);
            float yv2 = yAcc[2] + __shfl_xor(yAcc[2], 32);
            float yv3 = yAcc[3] + __shfl_xor(yAcc[3], 32);
            if (g < 2) {
                float4 ys; ys.x = yv0; ys.y = yv1; ys.z = yv2; ys.w = yv3;
                *reinterpret_cast<float4*>(out + (size_t)B * 16 + (size_t)(rowbase + j2) * 8 + g4) = ys;
            }
        }
    }
}

extern "C" void kernel_launch(void* const* d_in, const int* in_sizes, int n_in,
                              void* d_out, int out_size, void* d_ws, size_t ws_size,
                              hipStream_t stream) {
    const float* zg   = (const float*)d_in[0];
    const float* ug   = (const float*)d_in[1];
    const float* Wh1  = (const float*)d_in[2];
    const float* bh1  = (const float*)d_in[3];
    const float* Wh2  = (const float*)d_in[4];
    const float* W1jr = (const float*)d_in[5];
    const float* b1jr = (const float*)d_in[6];
    const float* W2jr = (const float*)d_in[7];
    const float* b2jr = (const float*)d_in[8];
    const float* W3jr = (const float*)d_in[9];
    const float* b3jr = (const float*)d_in[10];
    const float* W1b  = (const float*)d_in[11];
    const float* b1b  = (const float*)d_in[12];
    const float* W2b  = (const float*)d_in[13];
    const float* b2b  = (const float*)d_in[14];
    const float* W3b  = (const float*)d_in[15];
    const float* b3b  = (const float*)d_in[16];

    short* ws = (short*)d_ws;                       // 208 KB
    const int B = in_sizes[0] / 16;

    hipLaunchKernelGGL(pack_weights, dim3((NTILES * 64 + 255) / 256), dim3(256), 0, stream,
                       Wh1, bh1, Wh2, W1jr, b1jr, W2jr, W3jr, W1b, b1b, W2b, W3b, ws);

    const int grid = (B + 63) / 64;                 // 64 rows/block (4 waves x 16)
    hipLaunchKernelGGL(ph_mfma_kernel, dim3(grid), dim3(THREADS), 0, stream,
                       zg, ug, b2jr, b3jr, b2b, b3b, ws, (float*)d_out, B);
}

// Round 6
// 379.097 us; speedup vs baseline: 1.5353x; 1.5353x over previous
//
#include <hip/hip_runtime.h>

#define THREADS 256
#define MU_C  0.1f
#define EPS_C 0.01f

typedef short bf16x8 __attribute__((ext_vector_type(8)));
typedef bf16x8 bf16x8_a __attribute__((may_alias));
typedef float f32x4 __attribute__((ext_vector_type(4)));
typedef f32x4 f32x4_a __attribute__((may_alias));
typedef float f32_a __attribute__((may_alias));
typedef unsigned uint2v __attribute__((ext_vector_type(2)));
typedef uint2v uint2_a __attribute__((may_alias));
typedef unsigned u32_a __attribute__((may_alias));

#define MFMA(a, b, c) __builtin_amdgcn_mfma_f32_16x16x32_bf16((a), (b), (c), 0, 0, 0)

// ---- prepacked tile enumeration (1 tile = 64 lanes x 16B = 1 KB in d_ws) ----
#define T_WH1   0     // 8  : K=16pad32, bias bh1 at k=16
#define T_WH2   8     // 4  : K=128
#define T_WH2T  12    // 8  : K=16pad32 (no bias)
#define T_WH1T  20    // 4  : K=128
#define T_W1JR  24    // 4  : K=16pad32, bias b1jr at k=16
#define T_W2JR  28    // 8  : K=64
#define T_JMN   36    // 32 : Jm normal slabs n=0..15
#define T_JMT   68    // 32 : Jm transposed slabs t=0..15
#define T_RFN   100   // 32 : Rf normal
#define T_RFT   132   // 32 : Rf transposed
#define T_W1B   164   // 4  : K=16pad32, bias b1b at k=16
#define T_W2B   168   // 8  : K=64
#define T_BMN   176   // 16 : Bmat normal n=0..7
#define T_BMT   192   // 16 : Bmat transposed m=0..7
#define NTILES  208

__device__ __forceinline__ float ftanh(float x) {
    float e = __builtin_amdgcn_exp2f(x * 2.88539008177792681472f);
    return 1.0f - 2.0f * __builtin_amdgcn_rcpf(e + 1.0f);
}
__device__ __forceinline__ short bfrn(float f) {
    unsigned u = __float_as_uint(f);
    return (short)((u + 0x8000u) >> 16);
}
__device__ __forceinline__ float bf2f(unsigned lo16) {
    return __uint_as_float(lo16 << 16);
}
__device__ __forceinline__ unsigned pk2(float lo, float hi) {
    return ((unsigned)(unsigned short)bfrn(hi) << 16) | (unsigned short)bfrn(lo);
}
__device__ __forceinline__ bf16x8 wsB(const short* __restrict__ ws, int tile, int lane) {
    return *reinterpret_cast<const bf16x8*>(ws + (size_t)((tile << 6) + lane) * 8);
}
__device__ __forceinline__ bf16x8 ldsA(const short* base, int strideS, int lane, int k0) {
    return *reinterpret_cast<const bf16x8_a*>(base + (lane & 15) * strideS + k0 + (lane >> 4) * 8);
}

// ==================== weight pre-pack kernel ====================
__global__ __launch_bounds__(256)
void pack_weights(const float* __restrict__ Wh1, const float* __restrict__ bh1,
                  const float* __restrict__ Wh2,
                  const float* __restrict__ W1jr, const float* __restrict__ b1jr,
                  const float* __restrict__ W2jr, const float* __restrict__ W3jr,
                  const float* __restrict__ W1b, const float* __restrict__ b1b,
                  const float* __restrict__ W2b, const float* __restrict__ W3b,
                  short* __restrict__ ws)
{
    const int id = blockIdx.x * 256 + threadIdx.x;
    if (id >= NTILES * 64) return;
    const int tile = id >> 6, lane = id & 63;
    const int j2 = lane & 15, g = lane >> 4;
    bf16x8 f;
#pragma unroll
    for (int jj = 0; jj < 8; ++jj) {
        const int k = g * 8 + jj;
        float x = 0.f;
        if (tile < T_WH2) {
            int n0 = (tile - T_WH1) * 16;
            if (g < 2) x = Wh1[(n0 + j2) * 16 + k];
            else if (k == 16) x = bh1[n0 + j2];
        } else if (tile < T_WH2T) {
            int kt = tile - T_WH2;
            x = Wh2[j2 * 128 + kt * 32 + k];
        } else if (tile < T_WH1T) {
            if (g < 2) x = Wh2[k * 128 + (tile - T_WH2T) * 16 + j2];
        } else if (tile < T_W1JR) {
            int kt = tile - T_WH1T;
            x = Wh1[(kt * 32 + k) * 16 + j2];
        } else if (tile < T_W2JR) {
            int n0 = (tile - T_W1JR) * 16;
            if (g < 2) x = W1jr[(n0 + j2) * 16 + k];
            else if (k == 16) x = b1jr[n0 + j2];
        } else if (tile < T_JMN) {
            int q = tile - T_W2JR; int nt = q >> 1, kt = q & 1;
            x = W2jr[(nt * 16 + j2) * 64 + kt * 32 + k];
        } else if (tile < T_JMT) {
            int q = tile - T_JMN; int n = q >> 1, kt = q & 1;
            x = W3jr[(n * 16 + j2) * 64 + kt * 32 + k];
        } else if (tile < T_RFN) {
            int q = tile - T_JMT; int t = q >> 1, kt = q & 1;
            x = W3jr[(j2 * 16 + t) * 64 + kt * 32 + k];
        } else if (tile < T_RFT) {
            int q = tile - T_RFN; int n = q >> 1, kt = q & 1;
            x = W3jr[(256 + n * 16 + j2) * 64 + kt * 32 + k];
        } else if (tile < T_W1B) {
            int q = tile - T_RFT; int t = q >> 1, kt = q & 1;
            x = W3jr[(256 + j2 * 16 + t) * 64 + kt * 32 + k];
        } else if (tile < T_W2B) {
            int n0 = (tile - T_W1B) * 16;
            if (g < 2) x = W1b[(n0 + j2) * 16 + k];
            else if (k == 16) x = b1b[n0 + j2];
        } else if (tile < T_BMN) {
            int q = tile - T_W2B; int nt = q >> 1, kt = q & 1;
            x = W2b[(nt * 16 + j2) * 64 + kt * 32 + k];
        } else if (tile < T_BMT) {
            int q = tile - T_BMN; int n = q >> 1, kt = q & 1;
            x = W3b[(n * 16 + j2) * 64 + kt * 32 + k];
        } else {
            int q = tile - T_BMT; int m = q >> 1, kt = q & 1;
            x = W3b[(j2 * 8 + m) * 64 + kt * 32 + k];
        }
        f[jj] = bfrn(x);
    }
    reinterpret_cast<bf16x8*>(ws)[id] = f;
}

// ==================== main kernel ====================
// Weights = MFMA A operand, activations = B operand -> C = [feat x batch];
// lane (j2,g) holds feats g*4..g*4+3 of batch row j2 (epilogues lane-local).
struct __align__(16) WaveLds {
    short zt [16 * 40];    // z bf16, col16 = 1.0 (bias slot), 17..31 = 0
    short fvt[16 * 40];    // fv bf16, cols 16..31 = 0
    char  act[4608];       // overlay: t1[16][136]s | {h1t[16][72]s, h2t[16][72]s @2304 | rfv f32[16][20] @2304}
    float gHf[16 * 20];    // gH f32 [batch][feat]
};
struct __align__(16) BlockLds {
    WaveLds w[4];
    float bias[768];       // 0 b2jr(64) | 64 b3jr(512) | 576 b2b(64) | 640 b3b(128)
};

__global__ __launch_bounds__(THREADS)    // NO min-waves arg: round-5's (,4) forced a
                                         // 64-VGPR clamp -> 1.4 GB scratch spill
void ph_mfma_kernel(const float* __restrict__ zg, const float* __restrict__ ug,
                    const float* __restrict__ b2jr, const float* __restrict__ b3jr,
                    const float* __restrict__ b2b, const float* __restrict__ b3b,
                    const short* __restrict__ ws,
                    float* __restrict__ out, int B)
{
    __shared__ BlockLds L;
    const int tid  = threadIdx.x;
    const int lane = tid & 63;
    const int wid  = tid >> 6;
    const int j2   = lane & 15;
    const int g    = lane >> 4;
    const int g4   = g * 4;
    const int rowbase = blockIdx.x * 64 + wid * 16;
    if (blockIdx.x * 64 >= B) return;

    WaveLds& Wv = L.w[wid];
    short* t1s = (short*)Wv.act;                 // stride 136
    short* h1t = (short*)Wv.act;                 // stride 72
    short* h2t = (short*)(Wv.act + 2304);        // stride 72
    float* rfv = (float*)(Wv.act + 2304);        // stride 20 (overlays h2t; disjoint lifetime)

    // ---- block prologue: biases ----
    for (int i = tid; i < 768; i += THREADS) {
        float v;
        if      (i < 64)  v = b2jr[i];
        else if (i < 576) v = b3jr[i - 64];
        else if (i < 640) v = b2b[i - 576];
        else              v = b3b[i - 640];
        L.bias[i] = v;
    }
    // ---- per-wave prologue ----
    if (lane < 16) {   // zt pad: col16 = 1.0, 17..31 = 0 ; fvt pad: 16..31 = 0
        u32_a* p = (u32_a*)&Wv.zt[lane * 40 + 16];
        p[0] = 0x00003F80u;
#pragma unroll
        for (int i = 1; i < 8; ++i) p[i] = 0u;
        u32_a* q = (u32_a*)&Wv.fvt[lane * 40 + 16];
#pragma unroll
        for (int i = 0; i < 8; ++i) q[i] = 0u;
    }
    float zReg[4];
    {
        float4 zv = *reinterpret_cast<const float4*>(zg + (size_t)(rowbase + j2) * 16 + g4);
        zReg[0] = zv.x; zReg[1] = zv.y; zReg[2] = zv.z; zReg[3] = zv.w;
        *(uint2_a*)&Wv.zt[j2 * 40 + g4] = (uint2v){pk2(zv.x, zv.y), pk2(zv.z, zv.w)};
    }
    float uReg[8];
    {
        const float4* up = reinterpret_cast<const float4*>(ug + (size_t)(rowbase + j2) * 8);
        float4 u0 = up[0], u1 = up[1];
        uReg[0]=u0.x; uReg[1]=u0.y; uReg[2]=u0.z; uReg[3]=u0.w;
        uReg[4]=u1.x; uReg[5]=u1.y; uReg[6]=u1.z; uReg[7]=u1.w;
    }
    __syncthreads();

#pragma unroll 1
    for (int pass = 0; pass < 2; ++pass) {
        bf16x8 bZ = ldsA(Wv.zt, 40, lane, 0);
        float dzAcc[4], fvReg[4];
        unsigned tPk[16];

        // ---- step1: t1 = tanh(Wh1 z + bh1)  [feat 128 x batch 16], bias via k16 ----
#pragma unroll
        for (int nt = 0; nt < 8; ++nt) {
            f32x4 acc = {0.f, 0.f, 0.f, 0.f};
            acc = MFMA(wsB(ws, T_WH1 + nt, lane), bZ, acc);
            unsigned p0 = pk2(ftanh(acc[0]), ftanh(acc[1]));
            unsigned p1 = pk2(ftanh(acc[2]), ftanh(acc[3]));
            tPk[nt * 2] = p0; tPk[nt * 2 + 1] = p1;
            *(uint2_a*)&t1s[j2 * 136 + nt * 16 + g4] = (uint2v){p0, p1};
        }
        // ---- step2: fv = mu z + Wh2 t1  [16 x batch], K=128 ----
        {
            f32x4 acc = {0.f, 0.f, 0.f, 0.f};
#pragma unroll
            for (int kt = 0; kt < 4; ++kt)
                acc = MFMA(wsB(ws, T_WH2 + kt, lane), ldsA(t1s, 136, lane, kt * 32), acc);
#pragma unroll
            for (int r = 0; r < 4; ++r) fvReg[r] = acc[r] + MU_C * zReg[r];
            *(uint2_a*)&Wv.fvt[j2 * 40 + g4] = (uint2v){pk2(fvReg[0], fvReg[1]), pk2(fvReg[2], fvReg[3])};
        }
        // ---- step3: s = (1-t1^2) * (Wh2^T fv), t1 from regs, s -> t1 LDS ----
        {
            bf16x8 bF = ldsA(Wv.fvt, 40, lane, 0);
#pragma unroll
            for (int nt = 0; nt < 8; ++nt) {
                f32x4 acc = {0.f, 0.f, 0.f, 0.f};
                acc = MFMA(wsB(ws, T_WH2T + nt, lane), bF, acc);
                float t0 = bf2f(tPk[nt * 2] & 0xffffu),  t1v = bf2f(tPk[nt * 2] >> 16);
                float t2 = bf2f(tPk[nt * 2 + 1] & 0xffffu), t3 = bf2f(tPk[nt * 2 + 1] >> 16);
                unsigned p0 = pk2((1.f - t0 * t0) * acc[0], (1.f - t1v * t1v) * acc[1]);
                unsigned p1 = pk2((1.f - t2 * t2) * acc[2], (1.f - t3 * t3) * acc[3]);
                *(uint2_a*)&t1s[j2 * 136 + nt * 16 + g4] = (uint2v){p0, p1};
            }
        }
        // ---- step4: gH = mu fv + Wh1^T s  [16 x batch], K=128 ----
        {
            f32x4 acc = {0.f, 0.f, 0.f, 0.f};
#pragma unroll
            for (int kt = 0; kt < 4; ++kt)
                acc = MFMA(wsB(ws, T_WH1T + kt, lane), ldsA(t1s, 136, lane, kt * 32), acc);
            float gh0 = acc[0] + MU_C * fvReg[0], gh1 = acc[1] + MU_C * fvReg[1];
            float gh2 = acc[2] + MU_C * fvReg[2], gh3 = acc[3] + MU_C * fvReg[3];
            *(f32x4_a*)&Wv.gHf[j2 * 20 + g4] = (f32x4){gh0, gh1, gh2, gh3};
            dzAcc[0] = -EPS_C * gh0; dzAcc[1] = -EPS_C * gh1;
            dzAcc[2] = -EPS_C * gh2; dzAcc[3] = -EPS_C * gh3;
        }
        // ---- step5: h1 = tanh(W1jr z + b1jr), bias via k16 ----
#pragma unroll
        for (int nt = 0; nt < 4; ++nt) {
            f32x4 acc = {0.f, 0.f, 0.f, 0.f};
            acc = MFMA(wsB(ws, T_W1JR + nt, lane), bZ, acc);
            *(uint2_a*)&h1t[j2 * 72 + nt * 16 + g4] =
                (uint2v){pk2(ftanh(acc[0]), ftanh(acc[1])), pk2(ftanh(acc[2]), ftanh(acc[3]))};
        }
        // ---- step6: h2 = tanh(W2jr h1 + b2jr) ----
        {
            bf16x8 b0 = ldsA(h1t, 72, lane, 0);
            bf16x8 b1 = ldsA(h1t, 72, lane, 32);
#pragma unroll
            for (int nt = 0; nt < 4; ++nt) {
                f32x4 acc = {0.f, 0.f, 0.f, 0.f};
                acc = MFMA(wsB(ws, T_W2JR + nt * 2 + 0, lane), b0, acc);
                acc = MFMA(wsB(ws, T_W2JR + nt * 2 + 1, lane), b1, acc);
                *(uint2_a*)&h2t[j2 * 72 + nt * 16 + g4] =
                    (uint2v){pk2(ftanh(acc[0] + L.bias[nt * 16 + g4 + 0]),
                                 ftanh(acc[1] + L.bias[nt * 16 + g4 + 1])),
                             pk2(ftanh(acc[2] + L.bias[nt * 16 + g4 + 2]),
                                 ftanh(acc[3] + L.bias[nt * 16 + g4 + 3]))};
            }
        }
        // ---- step7: dz += (J - R) gH ----
        {
            bf16x8 bH0 = ldsA(h2t, 72, lane, 0);
            bf16x8 bH1 = ldsA(h2t, 72, lane, 32);
            // Jm normal: dz_j -= Jm[n][j] gH[n]   (the -Jm^T gH part)
#pragma unroll 2
            for (int n = 0; n < 16; ++n) {
                f32x4 acc = {0.f, 0.f, 0.f, 0.f};
                acc = MFMA(wsB(ws, T_JMN + 2 * n + 0, lane), bH0, acc);
                acc = MFMA(wsB(ws, T_JMN + 2 * n + 1, lane), bH1, acc);
                float gh = *(const f32_a*)&Wv.gHf[j2 * 20 + n];
#pragma unroll
                for (int r = 0; r < 4; ++r)
                    dzAcc[r] -= (acc[r] + L.bias[64 + n * 16 + g4 + r]) * gh;
            }
            // Jm transposed: dz_i += Jm[i][t] gH[t]
#pragma unroll 2
            for (int t = 0; t < 16; ++t) {
                f32x4 acc = {0.f, 0.f, 0.f, 0.f};
                acc = MFMA(wsB(ws, T_JMT + 2 * t + 0, lane), bH0, acc);
                acc = MFMA(wsB(ws, T_JMT + 2 * t + 1, lane), bH1, acc);
                float gh = *(const f32_a*)&Wv.gHf[j2 * 20 + t];
#pragma unroll
                for (int r = 0; r < 4; ++r)
                    dzAcc[r] += (acc[r] + L.bias[64 + (g4 + r) * 16 + t]) * gh;
            }
            // Rf normal: rfv_j = Rf[n][j] gH[n]
            {
                float rAcc[4] = {0.f, 0.f, 0.f, 0.f};
#pragma unroll 2
                for (int n = 0; n < 16; ++n) {
                    f32x4 acc = {0.f, 0.f, 0.f, 0.f};
                    acc = MFMA(wsB(ws, T_RFN + 2 * n + 0, lane), bH0, acc);
                    acc = MFMA(wsB(ws, T_RFN + 2 * n + 1, lane), bH1, acc);
                    float gh = *(const f32_a*)&Wv.gHf[j2 * 20 + n];
#pragma unroll
                    for (int r = 0; r < 4; ++r)
                        rAcc[r] += (acc[r] + L.bias[320 + n * 16 + g4 + r]) * gh;
                }
                *(f32x4_a*)&rfv[j2 * 20 + g4] = (f32x4){rAcc[0], rAcc[1], rAcc[2], rAcc[3]};
            }
            // Rf transposed: dz_i -= Rf[i][t] rfv[t]
#pragma unroll 2
            for (int t = 0; t < 16; ++t) {
                f32x4 acc = {0.f, 0.f, 0.f, 0.f};
                acc = MFMA(wsB(ws, T_RFT + 2 * t + 0, lane), bH0, acc);
                acc = MFMA(wsB(ws, T_RFT + 2 * t + 1, lane), bH1, acc);
                float rv = *(const f32_a*)&rfv[j2 * 20 + t];
#pragma unroll
                for (int r = 0; r < 4; ++r)
                    dzAcc[r] -= (acc[r] + L.bias[320 + (g4 + r) * 16 + t]) * rv;
            }
        }
        // ---- step8: g1,g2 (B-net, reuse h1t/h2t; rfv dead) ----
#pragma unroll
        for (int nt = 0; nt < 4; ++nt) {
            f32x4 acc = {0.f, 0.f, 0.f, 0.f};
            acc = MFMA(wsB(ws, T_W1B + nt, lane), bZ, acc);
            *(uint2_a*)&h1t[j2 * 72 + nt * 16 + g4] =
                (uint2v){pk2(ftanh(acc[0]), ftanh(acc[1])), pk2(ftanh(acc[2]), ftanh(acc[3]))};
        }
        {
            bf16x8 b0 = ldsA(h1t, 72, lane, 0);
            bf16x8 b1 = ldsA(h1t, 72, lane, 32);
#pragma unroll
            for (int nt = 0; nt < 4; ++nt) {
                f32x4 acc = {0.f, 0.f, 0.f, 0.f};
                acc = MFMA(wsB(ws, T_W2B + nt * 2 + 0, lane), b0, acc);
                acc = MFMA(wsB(ws, T_W2B + nt * 2 + 1, lane), b1, acc);
                *(uint2_a*)&h2t[j2 * 72 + nt * 16 + g4] =
                    (uint2v){pk2(ftanh(acc[0] + L.bias[576 + nt * 16 + g4 + 0]),
                                 ftanh(acc[1] + L.bias[576 + nt * 16 + g4 + 1])),
                             pk2(ftanh(acc[2] + L.bias[576 + nt * 16 + g4 + 2]),
                                 ftanh(acc[3] + L.bias[576 + nt * 16 + g4 + 3]))};
            }
        }
        // ---- step9: y (normal) and Bu (transposed) ----
        float yAcc[4] = {0.f, 0.f, 0.f, 0.f};
        {
            bf16x8 b0 = ldsA(h2t, 72, lane, 0);
            bf16x8 b1 = ldsA(h2t, 72, lane, 32);
#pragma unroll
            for (int n = 0; n < 8; ++n) {      // rows q=g4+r -> d=2n+(g>>1), m=q&7
                f32x4 acc = {0.f, 0.f, 0.f, 0.f};
                acc = MFMA(wsB(ws, T_BMN + 2 * n + 0, lane), b0, acc);
                acc = MFMA(wsB(ws, T_BMN + 2 * n + 1, lane), b1, acc);
                float gh = *(const f32_a*)&Wv.gHf[j2 * 20 + 2 * n + (g >> 1)];
#pragma unroll
                for (int r = 0; r < 4; ++r)
                    yAcc[r] += (acc[r] + L.bias[640 + n * 16 + g4 + r]) * gh;
            }
#pragma unroll
            for (int m = 0; m < 8; ++m) {      // rows = d; dz_d += B[d][m] u[m]
                f32x4 acc = {0.f, 0.f, 0.f, 0.f};
                acc = MFMA(wsB(ws, T_BMT + 2 * m + 0, lane), b0, acc);
                acc = MFMA(wsB(ws, T_BMT + 2 * m + 1, lane), b1, acc);
                float um = uReg[m];
#pragma unroll
                for (int r = 0; r < 4; ++r)
                    dzAcc[r] += (acc[r] + L.bias[640 + (g4 + r) * 8 + m]) * um;
            }
        }
        // ---- pass epilogue ----
        float* op = out + (size_t)(rowbase + j2) * 16 + g4;
        if (pass == 0) {
            float4 o;
            o.x = zReg[0] + 0.5f * dzAcc[0]; o.y = zReg[1] + 0.5f * dzAcc[1];
            o.z = zReg[2] + 0.5f * dzAcc[2]; o.w = zReg[3] + 0.5f * dzAcc[3];
            *reinterpret_cast<float4*>(op) = o;
#pragma unroll
            for (int r = 0; r < 4; ++r) zReg[r] += dzAcc[r];     // z1
            *(uint2_a*)&Wv.zt[j2 * 40 + g4] = (uint2v){pk2(zReg[0], zReg[1]), pk2(zReg[2], zReg[3])};
        } else {
            float4 o = *reinterpret_cast<const float4*>(op);
            o.x += 0.5f * dzAcc[0]; o.y += 0.5f * dzAcc[1];
            o.z += 0.5f * dzAcc[2]; o.w += 0.5f * dzAcc[3];
            *reinterpret_cast<float4*>(op) = o;
            float yv0 = yAcc[0] + __shfl_xor(yAcc[0], 32);
            float yv1 = yAcc[1] + __shfl_xor(yAcc[1], 32);
            float yv2 = yAcc[2] + __shfl_xor(yAcc[2], 32);
            float yv3 = yAcc[3] + __shfl_xor(yAcc[3], 32);
            if (g < 2) {
                float4 ys; ys.x = yv0; ys.y = yv1; ys.z = yv2; ys.w = yv3;
                *reinterpret_cast<float4*>(out + (size_t)B * 16 + (size_t)(rowbase + j2) * 8 + g4) = ys;
            }
        }
    }
}

extern "C" void kernel_launch(void* const* d_in, const int* in_sizes, int n_in,
                              void* d_out, int out_size, void* d_ws, size_t ws_size,
                              hipStream_t stream) {
    const float* zg   = (const float*)d_in[0];
    const float* ug   = (const float*)d_in[1];
    const float* Wh1  = (const float*)d_in[2];
    const float* bh1  = (const float*)d_in[3];
    const float* Wh2  = (const float*)d_in[4];
    const float* W1jr = (const float*)d_in[5];
    const float* b1jr = (const float*)d_in[6];
    const float* W2jr = (const float*)d_in[7];
    const float* b2jr = (const float*)d_in[8];
    const float* W3jr = (const float*)d_in[9];
    const float* b3jr = (const float*)d_in[10];
    const float* W1b  = (const float*)d_in[11];
    const float* b1b  = (const float*)d_in[12];
    const float* W2b  = (const float*)d_in[13];
    const float* b2b  = (const float*)d_in[14];
    const float* W3b  = (const float*)d_in[15];
    const float* b3b  = (const float*)d_in[16];

    short* ws = (short*)d_ws;                       // 208 KB
    const int B = in_sizes[0] / 16;

    hipLaunchKernelGGL(pack_weights, dim3((NTILES * 64 + 255) / 256), dim3(256), 0, stream,
                       Wh1, bh1, Wh2, W1jr, b1jr, W2jr, W3jr, W1b, b1b, W2b, W3b, ws);

    const int grid = (B + 63) / 64;                 // 64 rows/block (4 waves x 16)
    hipLaunchKernelGGL(ph_mfma_kernel, dim3(grid), dim3(THREADS), 0, stream,
                       zg, ug, b2jr, b3jr, b2b, b3b, ws, (float*)d_out, B);
}